// Round 1
// 436.057 us; speedup vs baseline: 1.0544x; 1.0544x over previous
//
#include <hip/hip_runtime.h>

// Problem constants: B=512, D=1024, H1=512, H2=128
// Outputs (f32, concat): recover [512,1024], c2 [512,128], Jac [512,128,1024]
//
// R1 package vs previous 460µs version:
//  - 7 launches -> 4 (prep||gemm1, gemm2, gemm3||build_A, recover||Jac)
//  - T1 chunked XCD swizzle on the 4096 Jac blocks (A_all panel reuse in own-XCD L2)
//  - gemm_f32: BK 16->32 + register prefetch pipeline (1 blk/CU -> must hide latency in-block)

typedef _Float16 f16x8 __attribute__((ext_vector_type(8)));
typedef _Float16 f16x4 __attribute__((ext_vector_type(4)));
typedef float    f32x4 __attribute__((ext_vector_type(4)));
typedef float    f32x2 __attribute__((ext_vector_type(2)));

__device__ __forceinline__ void gld_lds16(const _Float16* src, _Float16* dst_wave_uniform) {
    __builtin_amdgcn_global_load_lds((const __attribute__((address_space(1))) unsigned int*)src,
                                     (__attribute__((address_space(3))) unsigned int*)dst_wave_uniform,
                                     16, 0, 0);
}

// ---------------- prep: W1 transpose->f16, W2 ->f16 (device body) ----------------
__device__ __forceinline__ void prep_dev(int bx, const float* __restrict__ W1,
                                         const float* __restrict__ W2,
                                         _Float16* __restrict__ W1T,
                                         _Float16* __restrict__ W2h) {
    if (bx < 512) {
        __shared__ float tile[32][33];
        int dt = (bx & 31) * 32, kt = (bx >> 5) * 32;
        int tx = threadIdx.x & 31, ty = threadIdx.x >> 5;  // 32 x 8
        #pragma unroll
        for (int r = 0; r < 32; r += 8)
            tile[ty + r][tx] = W1[(kt + ty + r) * 1024 + dt + tx];
        __syncthreads();
        #pragma unroll
        for (int r = 0; r < 32; r += 8)
            W1T[(size_t)(dt + ty + r) * 512 + kt + tx] = (_Float16)tile[tx][ty + r];
    } else {
        int i = (bx - 512) * 1024 + threadIdx.x * 4;  // 64 blocks cover 65536
        f32x4 v = *(const f32x4*)(W2 + i);
        f16x4 h;
        h.x = (_Float16)v.x; h.y = (_Float16)v.y; h.z = (_Float16)v.z; h.w = (_Float16)v.w;
        *(f16x4*)(W2h + i) = h;
    }
}

// ---------------- small fp32 GEMMs (accuracy-critical path) ----------------
// 32x64 tile, 256 threads, per-thread 2x4. BK=32, register-prefetch pipeline.
// TRANSB=true: B is [N][K] (C=A@B^T).  EPI: 1 = sigmoid->C + Cd=s(1-s);  2 = sigmoid->Ch (f16)
template <int EPI, bool TRANSB>
__device__ void gemm_dev(const float* __restrict__ A, const float* __restrict__ Bm,
                         const float* __restrict__ bias,
                         float* __restrict__ C, float* __restrict__ Cd,
                         _Float16* __restrict__ Ch,
                         int M, int N, int K, int m0, int n0) {
    __shared__ __align__(16) float As[32][34];  // [k][m] (32 + pad)
    __shared__ __align__(16) float Bs[32][68];  // [k][n] (64 + pad)
    const int tid = threadIdx.x, tx = tid & 15, ty = tid >> 4;
    // staging index maps (coalesced in the fast dim)
    const int ka  = tid & 31, ma  = tid >> 5;   // A: rows m=ma+8r (r<4), col k=ka
    const int kbt = tid & 31, nbt = tid >> 5;   // B^T: rows n=nbt+8r (r<8), col k=kbt
    const int nbf = tid & 63, kbf = tid >> 6;   // B:   rows k=kbf+4r (r<8), col n=nbf
    float acc[2][4] = {};
    float rA[4], rB[8];

    // preload tile k0=0 into registers
    #pragma unroll
    for (int r = 0; r < 4; ++r) rA[r] = A[(size_t)(m0 + ma + 8 * r) * K + ka];
    if (TRANSB) {
        #pragma unroll
        for (int r = 0; r < 8; ++r) rB[r] = Bm[(size_t)(n0 + nbt + 8 * r) * K + kbt];
    } else {
        #pragma unroll
        for (int r = 0; r < 8; ++r) rB[r] = Bm[(size_t)(kbf + 4 * r) * N + n0 + nbf];
    }

    for (int k0 = 0; k0 < K; k0 += 32) {
        // regs -> LDS (prev compute finished at loop-end barrier)
        #pragma unroll
        for (int r = 0; r < 4; ++r) As[ka][ma + 8 * r] = rA[r];
        if (TRANSB) {
            #pragma unroll
            for (int r = 0; r < 8; ++r) Bs[kbt][nbt + 8 * r] = rB[r];
        } else {
            #pragma unroll
            for (int r = 0; r < 8; ++r) Bs[kbf + 4 * r][nbf] = rB[r];
        }
        // issue next tile's global loads now; latency hides under barrier+compute
        const int k1 = k0 + 32;
        if (k1 < K) {
            #pragma unroll
            for (int r = 0; r < 4; ++r) rA[r] = A[(size_t)(m0 + ma + 8 * r) * K + k1 + ka];
            if (TRANSB) {
                #pragma unroll
                for (int r = 0; r < 8; ++r) rB[r] = Bm[(size_t)(n0 + nbt + 8 * r) * K + k1 + kbt];
            } else {
                #pragma unroll
                for (int r = 0; r < 8; ++r) rB[r] = Bm[(size_t)(k1 + kbf + 4 * r) * N + n0 + nbf];
            }
        }
        __syncthreads();
        #pragma unroll
        for (int k = 0; k < 32; ++k) {
            f32x2 av = *(const f32x2*)&As[k][ty * 2];
            f32x4 bv = *(const f32x4*)&Bs[k][tx * 4];
            #pragma unroll
            for (int i = 0; i < 2; ++i)
                #pragma unroll
                for (int j = 0; j < 4; ++j)
                    acc[i][j] += av[i] * bv[j];
        }
        __syncthreads();
    }

    #pragma unroll
    for (int i = 0; i < 2; ++i) {
        int row = m0 + ty * 2 + i;
        #pragma unroll
        for (int j = 0; j < 4; ++j) {
            int col = n0 + tx * 4 + j;
            float z = acc[i][j] + bias[col];
            float s = 1.f / (1.f + __expf(-z));
            if constexpr (EPI == 1) {
                C[(size_t)row * N + col]  = s;
                Cd[(size_t)row * N + col] = s * (1.f - s);
            } else {
                Ch[(size_t)row * N + col] = (_Float16)s;
            }
        }
    }
}

// ---------------- build A_all[b][h][k] = f16(s2p[b][h]*W2[h][k]*s1p[b][k]) ----------------
__device__ __forceinline__ void buildA_dev(int b, const float* __restrict__ W2,
                                           const float* __restrict__ s1p,
                                           const float* __restrict__ s2p,
                                           _Float16* __restrict__ A_all) {
    const int tid = threadIdx.x;
    __shared__ float S1[512];
    __shared__ float S2[128];
    S1[tid]       = s1p[(size_t)b * 512 + tid];
    S1[tid + 256] = s1p[(size_t)b * 512 + tid + 256];
    if (tid < 128) S2[tid] = s2p[(size_t)b * 128 + tid];
    __syncthreads();
    _Float16* out = A_all + (size_t)b * 65536;
    #pragma unroll 4
    for (int i = 0; i < 32; ++i) {
        int c = tid + 256 * i;
        int h = c >> 6, k8 = (c & 63) * 8;
        f32x4 w0 = *(const f32x4*)(W2 + h * 512 + k8);
        f32x4 w1 = *(const f32x4*)(W2 + h * 512 + k8 + 4);
        float s2 = S2[h];
        f16x8 o;
        o[0] = (_Float16)(s2 * w0.x * S1[k8 + 0]);
        o[1] = (_Float16)(s2 * w0.y * S1[k8 + 1]);
        o[2] = (_Float16)(s2 * w0.z * S1[k8 + 2]);
        o[3] = (_Float16)(s2 * w0.w * S1[k8 + 3]);
        o[4] = (_Float16)(s2 * w1.x * S1[k8 + 4]);
        o[5] = (_Float16)(s2 * w1.y * S1[k8 + 5]);
        o[6] = (_Float16)(s2 * w1.z * S1[k8 + 6]);
        o[7] = (_Float16)(s2 * w1.w * S1[k8 + 7]);
        *(f16x8*)(out + h * 512 + k8) = o;
    }
}

// ---------------- fused launch wrappers ----------------
__global__ __launch_bounds__(256) void fused_prep_gemm1(const float* __restrict__ x,
                                                        const float* __restrict__ W1,
                                                        const float* __restrict__ b1,
                                                        const float* __restrict__ W2,
                                                        _Float16* __restrict__ W1T,
                                                        _Float16* __restrict__ W2h,
                                                        float* __restrict__ c1,
                                                        float* __restrict__ s1p) {
    int bx = blockIdx.x;
    if (bx < 128) {  // long pole first: c1 GEMM (K=1024)
        gemm_dev<1, true>(x, W1, b1, c1, s1p, nullptr, 512, 512, 1024,
                          (bx >> 3) * 32, (bx & 7) * 64);
    } else {
        prep_dev(bx - 128, W1, W2, W1T, W2h);
    }
}

__global__ __launch_bounds__(256) void gemm2_kernel(const float* __restrict__ c1,
                                                    const float* __restrict__ W2,
                                                    const float* __restrict__ b2,
                                                    float* __restrict__ out_c2,
                                                    float* __restrict__ s2p) {
    gemm_dev<1, true>(c1, W2, b2, out_c2, s2p, nullptr, 512, 128, 512,
                      blockIdx.y * 32, blockIdx.x * 64);
}

__global__ __launch_bounds__(256) void gemm3_kernel(const float* __restrict__ out_c2,
                                                    const float* __restrict__ W2,
                                                    const float* __restrict__ b3,
                                                    _Float16* __restrict__ c3h) {
    gemm_dev<2, false>(out_c2, W2, b3, nullptr, nullptr, c3h, 512, 512, 128,
                       (blockIdx.x >> 3) * 32, (blockIdx.x & 7) * 64);
}

__global__ __launch_bounds__(256) void fused_mid(const float* __restrict__ out_c2,
                                                 const float* __restrict__ W2,
                                                 const float* __restrict__ b3,
                                                 _Float16* __restrict__ c3h,
                                                 const float* __restrict__ s1p,
                                                 const float* __restrict__ s2p,
                                                 _Float16* __restrict__ A_all) {
    int bx = blockIdx.x;
    if (bx < 128) {
        gemm_dev<2, false>(out_c2, W2, b3, nullptr, nullptr, c3h, 512, 512, 128,
                           (bx >> 3) * 32, (bx & 7) * 64);
    } else {
        buildA_dev(bx - 128, W2, s1p, s2p, A_all);
    }
}

// ---------------- fused MFMA: recover (32 blocks) + Jac (4096 blocks, XCD-swizzled) ----------------
// Both are Out = A @ W1T^T (+bias): recover M=512, Jac per-batch M=128; K=512, N=1024.
__global__ __launch_bounds__(256) void fused_mfma(const _Float16* __restrict__ c3h,
                                                  const _Float16* __restrict__ A_all,
                                                  const _Float16* __restrict__ W1T,
                                                  const float* __restrict__ br,
                                                  float* __restrict__ out_rec,
                                                  float* __restrict__ out_jac) {
    __shared__ __align__(16) _Float16 Asl[128 * 64];  // [m][k]
    __shared__ __align__(16) _Float16 Bsl[128 * 64];  // [n][k]
    __shared__ float Bias[128];

    const int bid = blockIdx.x;
    const _Float16* A;
    float* Out;
    int m0, n0;
    bool has_bias;
    if (bid < 32) {                       // recover: grid 8(n) x 4(m)
        has_bias = true;
        A = c3h; Out = out_rec;
        n0 = (bid & 7) * 128; m0 = (bid >> 3) * 128;
    } else {                              // Jac: 4096 blocks, T1 chunked XCD swizzle
        int jid = bid - 32;               // bid%8 preserved (32%8==0)
        int w = (jid & 7) * 512 + (jid >> 3);  // bijective: XCD c owns batches [64c, 64c+64)
        int z = w >> 3;
        has_bias = false;
        A = A_all + (size_t)z * 65536;
        Out = out_jac + (size_t)z * 131072;
        n0 = (w & 7) * 128; m0 = 0;
    }
    const int K = 512, Nn = 1024;
    const int tid = threadIdx.x;
    const int lane = tid & 63, wave = tid >> 6;
    const int wm = (wave >> 1) * 64, wn = (wave & 1) * 64;
    const int l15 = lane & 15, q = lane >> 4;

    if (tid < 128) Bias[tid] = has_bias ? br[n0 + tid] : 0.f;

    f32x4 acc[4][4];
    #pragma unroll
    for (int i = 0; i < 4; ++i)
        #pragma unroll
        for (int j = 0; j < 4; ++j) acc[i][j] = (f32x4){0.f, 0.f, 0.f, 0.f};

    const int rbase = wave * 8 + (lane >> 3);
    const int kof   = (lane & 7) * 8;

    for (int k0 = 0; k0 < K; k0 += 64) {
        #pragma unroll
        for (int r = 0; r < 4; ++r) {
            gld_lds16(A   + (size_t)(m0 + r * 32 + rbase) * K + k0 + kof, Asl + (r * 32 + wave * 8) * 64);
            gld_lds16(W1T + (size_t)(n0 + r * 32 + rbase) * K + k0 + kof, Bsl + (r * 32 + wave * 8) * 64);
        }
        __syncthreads();
        #pragma unroll
        for (int kk = 0; kk < 64; kk += 32) {
            f16x8 af[4], bf[4];
            #pragma unroll
            for (int i = 0; i < 4; ++i)
                af[i] = *(const f16x8*)(Asl + (wm + i * 16 + l15) * 64 + kk + q * 8);
            #pragma unroll
            for (int j = 0; j < 4; ++j)
                bf[j] = *(const f16x8*)(Bsl + (wn + j * 16 + l15) * 64 + kk + q * 8);
            #pragma unroll
            for (int i = 0; i < 4; ++i)
                #pragma unroll
                for (int j = 0; j < 4; ++j)
                    acc[i][j] = __builtin_amdgcn_mfma_f32_16x16x32_f16(af[i], bf[j], acc[i][j], 0, 0, 0);
        }
        __syncthreads();
    }

    #pragma unroll
    for (int i = 0; i < 4; ++i) {
        #pragma unroll
        for (int rg = 0; rg < 4; ++rg) {
            int m = m0 + wm + i * 16 + q * 4 + rg;
            #pragma unroll
            for (int j = 0; j < 4; ++j) {
                int dcol = wn + j * 16 + l15;
                Out[(size_t)m * Nn + n0 + dcol] = acc[i][j][rg] + Bias[dcol];
            }
        }
    }
}

// ---------------- fallback path kernels (small workspace) ----------------
template <bool HAS_BIAS>
__global__ __launch_bounds__(256) void mfma_bt(const _Float16* __restrict__ Abase,
                                               const _Float16* __restrict__ Bmat,
                                               const float* __restrict__ bias,
                                               float* __restrict__ OutBase,
                                               int K, int N,
                                               long aBatch, long oBatch) {
    __shared__ __align__(16) _Float16 Asl[128 * 64];
    __shared__ __align__(16) _Float16 Bsl[128 * 64];
    __shared__ float Bias[128];
    const _Float16* A = Abase + (size_t)blockIdx.z * aBatch;
    float* Out = OutBase + (size_t)blockIdx.z * oBatch;
    const int m0 = blockIdx.y * 128, n0 = blockIdx.x * 128;
    const int tid = threadIdx.x;
    const int lane = tid & 63, wave = tid >> 6;
    const int wm = (wave >> 1) * 64, wn = (wave & 1) * 64;
    const int l15 = lane & 15, q = lane >> 4;

    if (HAS_BIAS && tid < 128) Bias[tid] = bias[n0 + tid];

    f32x4 acc[4][4];
    #pragma unroll
    for (int i = 0; i < 4; ++i)
        #pragma unroll
        for (int j = 0; j < 4; ++j) acc[i][j] = (f32x4){0.f, 0.f, 0.f, 0.f};

    const int rbase = wave * 8 + (lane >> 3);
    const int kof   = (lane & 7) * 8;

    for (int k0 = 0; k0 < K; k0 += 64) {
        #pragma unroll
        for (int r = 0; r < 4; ++r) {
            gld_lds16(A    + (size_t)(m0 + r * 32 + rbase) * K + k0 + kof, Asl + (r * 32 + wave * 8) * 64);
            gld_lds16(Bmat + (size_t)(n0 + r * 32 + rbase) * K + k0 + kof, Bsl + (r * 32 + wave * 8) * 64);
        }
        __syncthreads();
        #pragma unroll
        for (int kk = 0; kk < 64; kk += 32) {
            f16x8 af[4], bf[4];
            #pragma unroll
            for (int i = 0; i < 4; ++i)
                af[i] = *(const f16x8*)(Asl + (wm + i * 16 + l15) * 64 + kk + q * 8);
            #pragma unroll
            for (int j = 0; j < 4; ++j)
                bf[j] = *(const f16x8*)(Bsl + (wn + j * 16 + l15) * 64 + kk + q * 8);
            #pragma unroll
            for (int i = 0; i < 4; ++i)
                #pragma unroll
                for (int j = 0; j < 4; ++j)
                    acc[i][j] = __builtin_amdgcn_mfma_f32_16x16x32_f16(af[i], bf[j], acc[i][j], 0, 0, 0);
        }
        __syncthreads();
    }

    #pragma unroll
    for (int i = 0; i < 4; ++i) {
        #pragma unroll
        for (int rg = 0; rg < 4; ++rg) {
            int m = m0 + wm + i * 16 + q * 4 + rg;
            #pragma unroll
            for (int j = 0; j < 4; ++j) {
                int dcol = wn + j * 16 + l15;
                float v = acc[i][j][rg];
                if (HAS_BIAS) v += Bias[dcol];
                Out[(size_t)m * N + n0 + dcol] = v;
            }
        }
    }
}

__global__ __launch_bounds__(256) void jac_kernel(const _Float16* __restrict__ W2h,
                                                  const _Float16* __restrict__ W1T,
                                                  const float* __restrict__ s1p,
                                                  const float* __restrict__ s2p,
                                                  float* __restrict__ Jac) {
    __shared__ __align__(16) _Float16 Asl[128 * 64];
    __shared__ __align__(16) _Float16 Bsl[128 * 64];
    __shared__ float Ssl[128];
    const int b  = blockIdx.y;
    const int n0 = blockIdx.x * 128;
    const int tid = threadIdx.x;
    const int lane = tid & 63, wave = tid >> 6;
    const int wm = (wave >> 1) * 64, wn = (wave & 1) * 64;
    const int l15 = lane & 15, q = lane >> 4;

    if (tid < 128) Ssl[tid] = s2p[b * 128 + tid];

    f32x4 acc[4][4];
    #pragma unroll
    for (int i = 0; i < 4; ++i)
        #pragma unroll
        for (int j = 0; j < 4; ++j) acc[i][j] = (f32x4){0.f, 0.f, 0.f, 0.f};

    const int ah  = tid >> 4;
    const int akq = (tid & 15) * 4;
    const int rbase = wave * 8 + (lane >> 3);
    const int kof   = (lane & 7) * 8;

    for (int k0 = 0; k0 < 512; k0 += 64) {
        f32x4 s4 = *(const f32x4*)(s1p + (size_t)b * 512 + k0 + akq);
        f16x4 s4h;
        s4h.x = (_Float16)s4.x; s4h.y = (_Float16)s4.y;
        s4h.z = (_Float16)s4.z; s4h.w = (_Float16)s4.w;
        #pragma unroll
        for (int r = 0; r < 8; ++r) {
            int h = ah + r * 16;
            f16x4 w4 = *(const f16x4*)(W2h + (size_t)h * 512 + k0 + akq);
            *(f16x4*)(Asl + h * 64 + akq) = w4 * s4h;
        }
        #pragma unroll
        for (int r = 0; r < 4; ++r)
            gld_lds16(W1T + (size_t)(n0 + r * 32 + rbase) * 512 + k0 + kof,
                      Bsl + (r * 32 + wave * 8) * 64);
        __syncthreads();

        #pragma unroll
        for (int kk = 0; kk < 64; kk += 32) {
            f16x8 af[4], bf[4];
            #pragma unroll
            for (int i = 0; i < 4; ++i)
                af[i] = *(const f16x8*)(Asl + (wm + i * 16 + l15) * 64 + kk + q * 8);
            #pragma unroll
            for (int j = 0; j < 4; ++j)
                bf[j] = *(const f16x8*)(Bsl + (wn + j * 16 + l15) * 64 + kk + q * 8);
            #pragma unroll
            for (int i = 0; i < 4; ++i)
                #pragma unroll
                for (int j = 0; j < 4; ++j)
                    acc[i][j] = __builtin_amdgcn_mfma_f32_16x16x32_f16(af[i], bf[j], acc[i][j], 0, 0, 0);
        }
        __syncthreads();
    }

    float* outb = Jac + (size_t)b * (128 * 1024);
    #pragma unroll
    for (int i = 0; i < 4; ++i) {
        #pragma unroll
        for (int rg = 0; rg < 4; ++rg) {
            int h = wm + i * 16 + q * 4 + rg;
            float s = Ssl[h];
            #pragma unroll
            for (int j = 0; j < 4; ++j) {
                int d = n0 + wn + j * 16 + l15;
                outb[(size_t)h * 1024 + d] = acc[i][j][rg] * s;
            }
        }
    }
}

extern "C" void kernel_launch(void* const* d_in, const int* in_sizes, int n_in,
                              void* d_out, int out_size, void* d_ws, size_t ws_size,
                              hipStream_t stream) {
    const float* x  = (const float*)d_in[0];
    const float* W1 = (const float*)d_in[1];
    const float* b1 = (const float*)d_in[2];
    const float* W2 = (const float*)d_in[3];
    const float* b2 = (const float*)d_in[4];
    const float* b3 = (const float*)d_in[5];
    const float* br = (const float*)d_in[6];

    float* out_rec = (float*)d_out;               // 512*1024
    float* out_c2  = out_rec + 512 * 1024;        // 512*128
    float* out_jac = out_c2 + 512 * 128;          // 512*128*1024

    char* ws = (char*)d_ws;
    _Float16* W1T   = (_Float16*)(ws);             // 1 MB   [1024][512]
    _Float16* W2h   = (_Float16*)(ws + 0x100000);  // 128 KB [128][512]
    float*    c1    = (float*)(ws + 0x120000);     // 1 MB
    float*    s1p   = (float*)(ws + 0x220000);     // 1 MB
    float*    s2p   = (float*)(ws + 0x320000);     // 256 KB
    _Float16* c3h   = (_Float16*)(ws + 0x360000);  // 512 KB (ends 0x3E0000)
    _Float16* A_all = (_Float16*)(ws + 0x400000);  // 64 MB  [512][128][512]
    const bool big_ws = ws_size >= (size_t)0x4400000;

    // launch 1: c1 GEMM (128 blocks) + prep (576 blocks) share the machine
    fused_prep_gemm1<<<704, 256, 0, stream>>>(x, W1, b1, W2, W1T, W2h, c1, s1p);
    // launch 2: c2
    gemm2_kernel<<<dim3(2, 16), 256, 0, stream>>>(c1, W2, b2, out_c2, s2p);
    if (big_ws) {
        // launch 3: c3h GEMM (128 blocks) + build_A (512 blocks)
        fused_mid<<<640, 256, 0, stream>>>(out_c2, W2, b3, c3h, s1p, s2p, A_all);
        // launch 4: recover (32 blocks) + Jac (4096 blocks, XCD-swizzled)
        fused_mfma<<<4128, 256, 0, stream>>>(c3h, A_all, W1T, br, out_rec, out_jac);
    } else {
        gemm3_kernel<<<128, 256, 0, stream>>>(out_c2, W2, b3, c3h);
        mfma_bt<true><<<dim3(8, 4, 1), 256, 0, stream>>>(c3h, W1T, br, out_rec, 512, 1024, 0, 0);
        jac_kernel<<<dim3(8, 512), 256, 0, stream>>>(W2h, W1T, s1p, s2p, out_jac);
    }
}

// Round 2
// 431.635 us; speedup vs baseline: 1.0652x; 1.0102x over previous
//
#include <hip/hip_runtime.h>

// Problem constants: B=512, D=1024, H1=512, H2=128
// Outputs (f32, concat): recover [512,1024], c2 [512,128], Jac [512,128,1024]
//
// R2 vs R1 (436 µs):
//  - Jac GEMM rewritten as flat [65536x512]@[512x1024] with the 256^2 counted-vmcnt
//    double-buffered schedule (T2 swizzle + T3/T4 counted vmcnt(8) + T5 setprio + T14
//    stage-early), 512 threads, 128 KiB LDS dbuf, recover folded in as 8 extra blocks.
//  - XCD-chunked block swizzle on the 1024 Jac blocks (A-panel reuse in own-XCD L2).

typedef _Float16 f16x8 __attribute__((ext_vector_type(8)));
typedef _Float16 f16x4 __attribute__((ext_vector_type(4)));
typedef float    f32x4 __attribute__((ext_vector_type(4)));
typedef float    f32x2 __attribute__((ext_vector_type(2)));

__device__ __forceinline__ void gld_lds16(const _Float16* src, _Float16* dst_wave_uniform) {
    __builtin_amdgcn_global_load_lds((const __attribute__((address_space(1))) unsigned int*)src,
                                     (__attribute__((address_space(3))) unsigned int*)dst_wave_uniform,
                                     16, 0, 0);
}

// ---------------- prep: W1 transpose->f16, W2 ->f16 (device body) ----------------
__device__ __forceinline__ void prep_dev(int bx, const float* __restrict__ W1,
                                         const float* __restrict__ W2,
                                         _Float16* __restrict__ W1T,
                                         _Float16* __restrict__ W2h) {
    if (bx < 512) {
        __shared__ float tile[32][33];
        int dt = (bx & 31) * 32, kt = (bx >> 5) * 32;
        int tx = threadIdx.x & 31, ty = threadIdx.x >> 5;  // 32 x 8
        #pragma unroll
        for (int r = 0; r < 32; r += 8)
            tile[ty + r][tx] = W1[(kt + ty + r) * 1024 + dt + tx];
        __syncthreads();
        #pragma unroll
        for (int r = 0; r < 32; r += 8)
            W1T[(size_t)(dt + ty + r) * 512 + kt + tx] = (_Float16)tile[tx][ty + r];
    } else {
        int i = (bx - 512) * 1024 + threadIdx.x * 4;  // 64 blocks cover 65536
        f32x4 v = *(const f32x4*)(W2 + i);
        f16x4 h;
        h.x = (_Float16)v.x; h.y = (_Float16)v.y; h.z = (_Float16)v.z; h.w = (_Float16)v.w;
        *(f16x4*)(W2h + i) = h;
    }
}

// ---------------- small fp32 GEMMs (accuracy-critical path) ----------------
template <int EPI, bool TRANSB>
__device__ void gemm_dev(const float* __restrict__ A, const float* __restrict__ Bm,
                         const float* __restrict__ bias,
                         float* __restrict__ C, float* __restrict__ Cd,
                         _Float16* __restrict__ Ch,
                         int M, int N, int K, int m0, int n0) {
    __shared__ __align__(16) float As[32][34];  // [k][m] (32 + pad)
    __shared__ __align__(16) float Bs[32][68];  // [k][n] (64 + pad)
    const int tid = threadIdx.x, tx = tid & 15, ty = tid >> 4;
    const int ka  = tid & 31, ma  = tid >> 5;
    const int kbt = tid & 31, nbt = tid >> 5;
    const int nbf = tid & 63, kbf = tid >> 6;
    float acc[2][4] = {};
    float rA[4], rB[8];

    #pragma unroll
    for (int r = 0; r < 4; ++r) rA[r] = A[(size_t)(m0 + ma + 8 * r) * K + ka];
    if (TRANSB) {
        #pragma unroll
        for (int r = 0; r < 8; ++r) rB[r] = Bm[(size_t)(n0 + nbt + 8 * r) * K + kbt];
    } else {
        #pragma unroll
        for (int r = 0; r < 8; ++r) rB[r] = Bm[(size_t)(kbf + 4 * r) * N + n0 + nbf];
    }

    for (int k0 = 0; k0 < K; k0 += 32) {
        #pragma unroll
        for (int r = 0; r < 4; ++r) As[ka][ma + 8 * r] = rA[r];
        if (TRANSB) {
            #pragma unroll
            for (int r = 0; r < 8; ++r) Bs[kbt][nbt + 8 * r] = rB[r];
        } else {
            #pragma unroll
            for (int r = 0; r < 8; ++r) Bs[kbf + 4 * r][nbf] = rB[r];
        }
        const int k1 = k0 + 32;
        if (k1 < K) {
            #pragma unroll
            for (int r = 0; r < 4; ++r) rA[r] = A[(size_t)(m0 + ma + 8 * r) * K + k1 + ka];
            if (TRANSB) {
                #pragma unroll
                for (int r = 0; r < 8; ++r) rB[r] = Bm[(size_t)(n0 + nbt + 8 * r) * K + k1 + kbt];
            } else {
                #pragma unroll
                for (int r = 0; r < 8; ++r) rB[r] = Bm[(size_t)(k1 + kbf + 4 * r) * N + n0 + nbf];
            }
        }
        __syncthreads();
        #pragma unroll
        for (int k = 0; k < 32; ++k) {
            f32x2 av = *(const f32x2*)&As[k][ty * 2];
            f32x4 bv = *(const f32x4*)&Bs[k][tx * 4];
            #pragma unroll
            for (int i = 0; i < 2; ++i)
                #pragma unroll
                for (int j = 0; j < 4; ++j)
                    acc[i][j] += av[i] * bv[j];
        }
        __syncthreads();
    }

    #pragma unroll
    for (int i = 0; i < 2; ++i) {
        int row = m0 + ty * 2 + i;
        #pragma unroll
        for (int j = 0; j < 4; ++j) {
            int col = n0 + tx * 4 + j;
            float z = acc[i][j] + bias[col];
            float s = 1.f / (1.f + __expf(-z));
            if constexpr (EPI == 1) {
                C[(size_t)row * N + col]  = s;
                Cd[(size_t)row * N + col] = s * (1.f - s);
            } else {
                Ch[(size_t)row * N + col] = (_Float16)s;
            }
        }
    }
}

// ---------------- build A_all[b][h][k] = f16(s2p[b][h]*W2[h][k]*s1p[b][k]) ----------------
__device__ __forceinline__ void buildA_dev(int b, const float* __restrict__ W2,
                                           const float* __restrict__ s1p,
                                           const float* __restrict__ s2p,
                                           _Float16* __restrict__ A_all) {
    const int tid = threadIdx.x;
    __shared__ float S1[512];
    __shared__ float S2[128];
    S1[tid]       = s1p[(size_t)b * 512 + tid];
    S1[tid + 256] = s1p[(size_t)b * 512 + tid + 256];
    if (tid < 128) S2[tid] = s2p[(size_t)b * 128 + tid];
    __syncthreads();
    _Float16* out = A_all + (size_t)b * 65536;
    #pragma unroll 4
    for (int i = 0; i < 32; ++i) {
        int c = tid + 256 * i;
        int h = c >> 6, k8 = (c & 63) * 8;
        f32x4 w0 = *(const f32x4*)(W2 + h * 512 + k8);
        f32x4 w1 = *(const f32x4*)(W2 + h * 512 + k8 + 4);
        float s2 = S2[h];
        f16x8 o;
        o[0] = (_Float16)(s2 * w0.x * S1[k8 + 0]);
        o[1] = (_Float16)(s2 * w0.y * S1[k8 + 1]);
        o[2] = (_Float16)(s2 * w0.z * S1[k8 + 2]);
        o[3] = (_Float16)(s2 * w0.w * S1[k8 + 3]);
        o[4] = (_Float16)(s2 * w1.x * S1[k8 + 4]);
        o[5] = (_Float16)(s2 * w1.y * S1[k8 + 5]);
        o[6] = (_Float16)(s2 * w1.z * S1[k8 + 6]);
        o[7] = (_Float16)(s2 * w1.w * S1[k8 + 7]);
        *(f16x8*)(out + h * 512 + k8) = o;
    }
}

// ---------------- fused launch wrappers ----------------
__global__ __launch_bounds__(256) void fused_prep_gemm1(const float* __restrict__ x,
                                                        const float* __restrict__ W1,
                                                        const float* __restrict__ b1,
                                                        const float* __restrict__ W2,
                                                        _Float16* __restrict__ W1T,
                                                        _Float16* __restrict__ W2h,
                                                        float* __restrict__ c1,
                                                        float* __restrict__ s1p) {
    int bx = blockIdx.x;
    if (bx < 128) {
        gemm_dev<1, true>(x, W1, b1, c1, s1p, nullptr, 512, 512, 1024,
                          (bx >> 3) * 32, (bx & 7) * 64);
    } else {
        prep_dev(bx - 128, W1, W2, W1T, W2h);
    }
}

__global__ __launch_bounds__(256) void gemm2_kernel(const float* __restrict__ c1,
                                                    const float* __restrict__ W2,
                                                    const float* __restrict__ b2,
                                                    float* __restrict__ out_c2,
                                                    float* __restrict__ s2p) {
    gemm_dev<1, true>(c1, W2, b2, out_c2, s2p, nullptr, 512, 128, 512,
                      blockIdx.y * 32, blockIdx.x * 64);
}

__global__ __launch_bounds__(256) void gemm3_kernel(const float* __restrict__ out_c2,
                                                    const float* __restrict__ W2,
                                                    const float* __restrict__ b3,
                                                    _Float16* __restrict__ c3h) {
    gemm_dev<2, false>(out_c2, W2, b3, nullptr, nullptr, c3h, 512, 512, 128,
                       (blockIdx.x >> 3) * 32, (blockIdx.x & 7) * 64);
}

__global__ __launch_bounds__(256) void fused_mid(const float* __restrict__ out_c2,
                                                 const float* __restrict__ W2,
                                                 const float* __restrict__ b3,
                                                 _Float16* __restrict__ c3h,
                                                 const float* __restrict__ s1p,
                                                 const float* __restrict__ s2p,
                                                 _Float16* __restrict__ A_all) {
    int bx = blockIdx.x;
    if (bx < 128) {
        gemm_dev<2, false>(out_c2, W2, b3, nullptr, nullptr, c3h, 512, 512, 128,
                           (bx >> 3) * 32, (bx & 7) * 64);
    } else {
        buildA_dev(bx - 128, W2, s1p, s2p, A_all);
    }
}

// ---------------- 256^2 counted-vmcnt MFMA GEMM: recover (8 blocks) + Jac (1024 blocks) ----
// Out = A @ W1T^T (+bias). A rows are K=512-major f16. BM=BN=256, BK=64, 512 thr (8 waves).
// dbuf LDS 128 KiB; T2 XOR swizzle (16B-granule, slot^=(row&7)) via pre-swizzled gld source;
// T3/T4 counted vmcnt(8); T5 setprio; T14 stage-early.
__global__ __launch_bounds__(512, 2) void jac8_kernel(const _Float16* __restrict__ c3h,
                                                      const _Float16* __restrict__ A_all,
                                                      const _Float16* __restrict__ W1T,
                                                      const float* __restrict__ br,
                                                      float* __restrict__ out_rec,
                                                      float* __restrict__ out_jac) {
    __shared__ __align__(16) _Float16 Asl[2][256 * 64];
    __shared__ __align__(16) _Float16 Bsl[2][256 * 64];
    __shared__ float BiasS[256];

    const int bid = blockIdx.x;
    const _Float16* A;
    float* Out;
    int m0, n0;
    bool has_bias;
    if (bid < 8) {                 // recover: M=512 -> 2 m-tiles x 4 n-tiles
        has_bias = true;
        A = c3h; Out = out_rec;
        m0 = (bid >> 2) * 256; n0 = (bid & 3) * 256;
    } else {                       // Jac: 1024 blocks, XCD-chunked swizzle (bid%8 preserved)
        int jid = bid - 8;
        int w = (jid & 7) * 128 + (jid >> 3);   // XCD c owns w in [128c,128c+128)
        has_bias = false;
        A = A_all; Out = out_jac;
        m0 = (w >> 2) * 256; n0 = (w & 3) * 256;
    }

    const int tid = threadIdx.x;
    const int lane = tid & 63, wave = tid >> 6;
    const int wm = (wave >> 2) * 128, wn = (wave & 3) * 64;   // 2x4 wave grid, 128x64/wave
    const int l15 = lane & 15, q = lane >> 4;

    if (tid < 256) BiasS[tid] = has_bias ? br[n0 + tid] : 0.f;

    // staging geometry: 4 loads/thread/operand/K-tile; pre-swizzled global k-offset
    const int srow = wave * 8 + (lane >> 3);                    // row within 64-row group
    const int skof = ((lane & 7) ^ (lane >> 3)) * 8;            // f16 units
    const _Float16* Abase = A   + (size_t)m0 * 512;
    const _Float16* Bbase = W1T + (size_t)n0 * 512;

    auto STAGE = [&](int t) {
        const int buf = t & 1;
        const int kb = t * 64;
        #pragma unroll
        for (int r = 0; r < 4; ++r)
            gld_lds16(Abase + (size_t)(r * 64 + srow) * 512 + kb + skof,
                      &Asl[buf][(r * 64 + wave * 8) * 64]);
        #pragma unroll
        for (int r = 0; r < 4; ++r)
            gld_lds16(Bbase + (size_t)(r * 64 + srow) * 512 + kb + skof,
                      &Bsl[buf][(r * 64 + wave * 8) * 64]);
    };

    f32x4 acc[8][4];
    #pragma unroll
    for (int i = 0; i < 8; ++i)
        #pragma unroll
        for (int j = 0; j < 4; ++j) acc[i][j] = (f32x4){0.f, 0.f, 0.f, 0.f};

    STAGE(0);
    STAGE(1);

    const int swz = (l15 & 7) * 8;   // read-side XOR term (f16 units), row&7 == l15&7

    #pragma unroll 1
    for (int t = 0; t < 8; ++t) {
        if (t < 7) asm volatile("s_waitcnt vmcnt(8)" ::: "memory");
        else       asm volatile("s_waitcnt vmcnt(0)" ::: "memory");
        __builtin_amdgcn_s_barrier();
        const int buf = t & 1;
        const _Float16* As = &Asl[buf][0];
        const _Float16* Bs = &Bsl[buf][0];

        // kk = 0 fragments
        f16x8 a0[8], b0[4];
        #pragma unroll
        for (int i = 0; i < 8; ++i)
            a0[i] = *(const f16x8*)(As + (wm + i * 16 + l15) * 64 + ((0 + q * 8) ^ swz));
        #pragma unroll
        for (int j = 0; j < 4; ++j)
            b0[j] = *(const f16x8*)(Bs + (wn + j * 16 + l15) * 64 + ((0 + q * 8) ^ swz));

        __builtin_amdgcn_s_setprio(1);
        #pragma unroll
        for (int i = 0; i < 8; ++i)
            #pragma unroll
            for (int j = 0; j < 4; ++j)
                acc[i][j] = __builtin_amdgcn_mfma_f32_16x16x32_f16(a0[i], b0[j], acc[i][j], 0, 0, 0);
        __builtin_amdgcn_s_setprio(0);

        // kk = 32 fragments
        f16x8 a1[8], b1[4];
        #pragma unroll
        for (int i = 0; i < 8; ++i)
            a1[i] = *(const f16x8*)(As + (wm + i * 16 + l15) * 64 + ((32 + q * 8) ^ swz));
        #pragma unroll
        for (int j = 0; j < 4; ++j)
            b1[j] = *(const f16x8*)(Bs + (wn + j * 16 + l15) * 64 + ((32 + q * 8) ^ swz));

        asm volatile("s_waitcnt lgkmcnt(0)" ::: "memory");
        __builtin_amdgcn_s_barrier();          // all waves done reading buf[t&1]
        if (t + 2 < 8) STAGE(t + 2);           // overwrite buf[t&1] with tile t+2
        __builtin_amdgcn_sched_barrier(0);     // keep stage issue ahead of MFMA cluster

        __builtin_amdgcn_s_setprio(1);
        #pragma unroll
        for (int i = 0; i < 8; ++i)
            #pragma unroll
            for (int j = 0; j < 4; ++j)
                acc[i][j] = __builtin_amdgcn_mfma_f32_16x16x32_f16(a1[i], b1[j], acc[i][j], 0, 0, 0);
        __builtin_amdgcn_s_setprio(0);
    }

    #pragma unroll
    for (int i = 0; i < 8; ++i) {
        #pragma unroll
        for (int rg = 0; rg < 4; ++rg) {
            int m = m0 + wm + i * 16 + q * 4 + rg;
            #pragma unroll
            for (int j = 0; j < 4; ++j) {
                int col = wn + j * 16 + l15;
                Out[(size_t)m * 1024 + n0 + col] = acc[i][j][rg] + BiasS[col];
            }
        }
    }
}

// ---------------- fallback path kernels (small workspace) ----------------
template <bool HAS_BIAS>
__global__ __launch_bounds__(256) void mfma_bt(const _Float16* __restrict__ Abase,
                                               const _Float16* __restrict__ Bmat,
                                               const float* __restrict__ bias,
                                               float* __restrict__ OutBase,
                                               int K, int N,
                                               long aBatch, long oBatch) {
    __shared__ __align__(16) _Float16 Asl[128 * 64];
    __shared__ __align__(16) _Float16 Bsl[128 * 64];
    __shared__ float Bias[128];
    const _Float16* A = Abase + (size_t)blockIdx.z * aBatch;
    float* Out = OutBase + (size_t)blockIdx.z * oBatch;
    const int m0 = blockIdx.y * 128, n0 = blockIdx.x * 128;
    const int tid = threadIdx.x;
    const int lane = tid & 63, wave = tid >> 6;
    const int wm = (wave >> 1) * 64, wn = (wave & 1) * 64;
    const int l15 = lane & 15, q = lane >> 4;

    if (HAS_BIAS && tid < 128) Bias[tid] = bias[n0 + tid];

    f32x4 acc[4][4];
    #pragma unroll
    for (int i = 0; i < 4; ++i)
        #pragma unroll
        for (int j = 0; j < 4; ++j) acc[i][j] = (f32x4){0.f, 0.f, 0.f, 0.f};

    const int rbase = wave * 8 + (lane >> 3);
    const int kof   = (lane & 7) * 8;

    for (int k0 = 0; k0 < K; k0 += 64) {
        #pragma unroll
        for (int r = 0; r < 4; ++r) {
            gld_lds16(A    + (size_t)(m0 + r * 32 + rbase) * K + k0 + kof, Asl + (r * 32 + wave * 8) * 64);
            gld_lds16(Bmat + (size_t)(n0 + r * 32 + rbase) * K + k0 + kof, Bsl + (r * 32 + wave * 8) * 64);
        }
        __syncthreads();
        #pragma unroll
        for (int kk = 0; kk < 64; kk += 32) {
            f16x8 af[4], bf[4];
            #pragma unroll
            for (int i = 0; i < 4; ++i)
                af[i] = *(const f16x8*)(Asl + (wm + i * 16 + l15) * 64 + kk + q * 8);
            #pragma unroll
            for (int j = 0; j < 4; ++j)
                bf[j] = *(const f16x8*)(Bsl + (wn + j * 16 + l15) * 64 + kk + q * 8);
            #pragma unroll
            for (int i = 0; i < 4; ++i)
                #pragma unroll
                for (int j = 0; j < 4; ++j)
                    acc[i][j] = __builtin_amdgcn_mfma_f32_16x16x32_f16(af[i], bf[j], acc[i][j], 0, 0, 0);
        }
        __syncthreads();
    }

    #pragma unroll
    for (int i = 0; i < 4; ++i) {
        #pragma unroll
        for (int rg = 0; rg < 4; ++rg) {
            int m = m0 + wm + i * 16 + q * 4 + rg;
            #pragma unroll
            for (int j = 0; j < 4; ++j) {
                int dcol = wn + j * 16 + l15;
                float v = acc[i][j][rg];
                if (HAS_BIAS) v += Bias[dcol];
                Out[(size_t)m * N + n0 + dcol] = v;
            }
        }
    }
}

__global__ __launch_bounds__(256) void jac_kernel(const _Float16* __restrict__ W2h,
                                                  const _Float16* __restrict__ W1T,
                                                  const float* __restrict__ s1p,
                                                  const float* __restrict__ s2p,
                                                  float* __restrict__ Jac) {
    __shared__ __align__(16) _Float16 Asl[128 * 64];
    __shared__ __align__(16) _Float16 Bsl[128 * 64];
    __shared__ float Ssl[128];
    const int b  = blockIdx.y;
    const int n0 = blockIdx.x * 128;
    const int tid = threadIdx.x;
    const int lane = tid & 63, wave = tid >> 6;
    const int wm = (wave >> 1) * 64, wn = (wave & 1) * 64;
    const int l15 = lane & 15, q = lane >> 4;

    if (tid < 128) Ssl[tid] = s2p[b * 128 + tid];

    f32x4 acc[4][4];
    #pragma unroll
    for (int i = 0; i < 4; ++i)
        #pragma unroll
        for (int j = 0; j < 4; ++j) acc[i][j] = (f32x4){0.f, 0.f, 0.f, 0.f};

    const int ah  = tid >> 4;
    const int akq = (tid & 15) * 4;
    const int rbase = wave * 8 + (lane >> 3);
    const int kof   = (lane & 7) * 8;

    for (int k0 = 0; k0 < 512; k0 += 64) {
        f32x4 s4 = *(const f32x4*)(s1p + (size_t)b * 512 + k0 + akq);
        f16x4 s4h;
        s4h.x = (_Float16)s4.x; s4h.y = (_Float16)s4.y;
        s4h.z = (_Float16)s4.z; s4h.w = (_Float16)s4.w;
        #pragma unroll
        for (int r = 0; r < 8; ++r) {
            int h = ah + r * 16;
            f16x4 w4 = *(const f16x4*)(W2h + (size_t)h * 512 + k0 + akq);
            *(f16x4*)(Asl + h * 64 + akq) = w4 * s4h;
        }
        #pragma unroll
        for (int r = 0; r < 4; ++r)
            gld_lds16(W1T + (size_t)(n0 + r * 32 + rbase) * 512 + k0 + kof,
                      Bsl + (r * 32 + wave * 8) * 64);
        __syncthreads();

        #pragma unroll
        for (int kk = 0; kk < 64; kk += 32) {
            f16x8 af[4], bf[4];
            #pragma unroll
            for (int i = 0; i < 4; ++i)
                af[i] = *(const f16x8*)(Asl + (wm + i * 16 + l15) * 64 + kk + q * 8);
            #pragma unroll
            for (int j = 0; j < 4; ++j)
                bf[j] = *(const f16x8*)(Bsl + (wn + j * 16 + l15) * 64 + kk + q * 8);
            #pragma unroll
            for (int i = 0; i < 4; ++i)
                #pragma unroll
                for (int j = 0; j < 4; ++j)
                    acc[i][j] = __builtin_amdgcn_mfma_f32_16x16x32_f16(af[i], bf[j], acc[i][j], 0, 0, 0);
        }
        __syncthreads();
    }

    float* outb = Jac + (size_t)b * (128 * 1024);
    #pragma unroll
    for (int i = 0; i < 4; ++i) {
        #pragma unroll
        for (int rg = 0; rg < 4; ++rg) {
            int h = wm + i * 16 + q * 4 + rg;
            float s = Ssl[h];
            #pragma unroll
            for (int j = 0; j < 4; ++j) {
                int d = n0 + wn + j * 16 + l15;
                outb[(size_t)h * 1024 + d] = acc[i][j][rg] * s;
            }
        }
    }
}

extern "C" void kernel_launch(void* const* d_in, const int* in_sizes, int n_in,
                              void* d_out, int out_size, void* d_ws, size_t ws_size,
                              hipStream_t stream) {
    const float* x  = (const float*)d_in[0];
    const float* W1 = (const float*)d_in[1];
    const float* b1 = (const float*)d_in[2];
    const float* W2 = (const float*)d_in[3];
    const float* b2 = (const float*)d_in[4];
    const float* b3 = (const float*)d_in[5];
    const float* br = (const float*)d_in[6];

    float* out_rec = (float*)d_out;               // 512*1024
    float* out_c2  = out_rec + 512 * 1024;        // 512*128
    float* out_jac = out_c2 + 512 * 128;          // 512*128*1024

    char* ws = (char*)d_ws;
    _Float16* W1T   = (_Float16*)(ws);             // 1 MB   [1024][512]
    _Float16* W2h   = (_Float16*)(ws + 0x100000);  // 128 KB [128][512]
    float*    c1    = (float*)(ws + 0x120000);     // 1 MB
    float*    s1p   = (float*)(ws + 0x220000);     // 1 MB
    float*    s2p   = (float*)(ws + 0x320000);     // 256 KB
    _Float16* c3h   = (_Float16*)(ws + 0x360000);  // 512 KB (ends 0x3E0000)
    _Float16* A_all = (_Float16*)(ws + 0x400000);  // 64 MB  [512][128][512]
    const bool big_ws = ws_size >= (size_t)0x4400000;

    // launch 1: c1 GEMM (128 blocks) + prep (576 blocks)
    fused_prep_gemm1<<<704, 256, 0, stream>>>(x, W1, b1, W2, W1T, W2h, c1, s1p);
    // launch 2: c2
    gemm2_kernel<<<dim3(2, 16), 256, 0, stream>>>(c1, W2, b2, out_c2, s2p);
    if (big_ws) {
        // launch 3: c3h GEMM (128 blocks) + build_A (512 blocks)
        fused_mid<<<640, 256, 0, stream>>>(out_c2, W2, b3, c3h, s1p, s2p, A_all);
        // launch 4: recover (8 blocks) + Jac (1024 blocks), 256^2 counted-vmcnt schedule
        jac8_kernel<<<1032, 512, 0, stream>>>(c3h, A_all, W1T, br, out_rec, out_jac);
    } else {
        gemm3_kernel<<<128, 256, 0, stream>>>(out_c2, W2, b3, c3h);
        mfma_bt<true><<<dim3(8, 4, 1), 256, 0, stream>>>(c3h, W1T, br, out_rec, 512, 1024, 0, 0);
        jac_kernel<<<dim3(8, 512), 256, 0, stream>>>(W2h, W1T, s1p, s2p, out_jac);
    }
}